// Round 1
// baseline (422.412 us; speedup 1.0000x reference)
//
#include <hip/hip_runtime.h>
#include <math.h>

#define NN 1024
#define HID 64
#define HEADD 128
#define NODE_DIM 14
#define BATCH 32
#define CAP 64
#define ROWS (BATCH * NN)   // 32768

// ---------------- K1: adjacency -> CSR + degree^-1/2 ----------------
// One block per (b, i) row. Adjacency values are exactly 0.0 or 1.0, so
// degree == nnz count. Cap 64 (mean nnz ~11.2, overflow prob ~1e-17/row).
__global__ __launch_bounds__(256) void k_build(const float* __restrict__ adj,
                                               int* __restrict__ csr,
                                               int* __restrict__ nnz,
                                               float* __restrict__ dinv) {
    int row = blockIdx.x;                       // b*NN + i
    __shared__ int s_cnt;
    __shared__ int s_idx[CAP];
    if (threadIdx.x == 0) s_cnt = 0;
    __syncthreads();
    const float4* rp = reinterpret_cast<const float4*>(adj + (size_t)row * NN);
    float4 v = rp[threadIdx.x];                 // 256 threads * 4 floats = 1024
    int col0 = threadIdx.x * 4;
    float vv[4] = {v.x, v.y, v.z, v.w};
#pragma unroll
    for (int k = 0; k < 4; ++k) {
        if (vv[k] != 0.0f) {
            int p = atomicAdd(&s_cnt, 1);
            if (p < CAP) s_idx[p] = col0 + k;
        }
    }
    __syncthreads();
    int n = s_cnt < CAP ? s_cnt : CAP;
    if ((int)threadIdx.x < n) csr[row * CAP + threadIdx.x] = s_idx[threadIdx.x];
    if (threadIdx.x == 0) {
        nnz[row] = n;
        int d = s_cnt < 1 ? 1 : s_cnt;          // clip(degree, 1)
        dinv[row] = 1.0f / sqrtf((float)d);
    }
}

// ---------------- K2: g = x @ W1  ([ROWS,14] @ [14,64]) ----------------
__global__ __launch_bounds__(256) void k_xw1(const float* __restrict__ x,
                                             const float* __restrict__ W1,
                                             float* __restrict__ g) {
    __shared__ float sW[NODE_DIM * HID];        // 3.5 KB
    __shared__ float sx[4 * NODE_DIM];
    int row0 = blockIdx.x * 4;
    for (int i = threadIdx.x; i < NODE_DIM * HID; i += 256) sW[i] = W1[i];
    for (int i = threadIdx.x; i < 4 * NODE_DIM; i += 256)
        sx[i] = x[(size_t)row0 * NODE_DIM + i];
    __syncthreads();
    int c = threadIdx.x & 63, rl = threadIdx.x >> 6;
    float acc = 0.f;
#pragma unroll
    for (int d = 0; d < NODE_DIM; ++d) acc += sx[rl * NODE_DIM + d] * sW[d * HID + c];
    g[(size_t)(row0 + rl) * HID + c] = acc;
}

// ---------------- K: g = h @ W  ([ROWS,64] @ [64,64]) ----------------
__global__ __launch_bounds__(256) void k_hw(const float* __restrict__ h,
                                            const float* __restrict__ W,
                                            float* __restrict__ g) {
    __shared__ float sW[HID * HID];             // 16 KB
    __shared__ float sh[16 * HID];              // 4 KB
    int row0 = blockIdx.x * 16;
    for (int i = threadIdx.x; i < HID * HID; i += 256) sW[i] = W[i];
    for (int i = threadIdx.x; i < 16 * HID; i += 256)
        sh[i] = h[(size_t)row0 * HID + i];
    __syncthreads();
    int c = threadIdx.x & 63, rl0 = threadIdx.x >> 6;
    float acc[4] = {0.f, 0.f, 0.f, 0.f};
    for (int d = 0; d < HID; ++d) {
        float w = sW[d * HID + c];              // lanes consecutive: conflict-free
#pragma unroll
        for (int q = 0; q < 4; ++q)
            acc[q] += sh[(rl0 + 4 * q) * HID + d] * w;  // wave-uniform: broadcast
    }
#pragma unroll
    for (int q = 0; q < 4; ++q)
        g[(size_t)(row0 + rl0 + 4 * q) * HID + c] = acc[q];
}

// ---------------- K: hout = relu(dinv_i * sum_j dinv_j * m_j + bias) ----------------
// One wave per row; lane = feature (HID == wavefront size == 64).
__global__ __launch_bounds__(256) void k_spmm(const float* __restrict__ m,
                                              const int* __restrict__ csr,
                                              const int* __restrict__ nnz,
                                              const float* __restrict__ dinv,
                                              const float* __restrict__ bias,
                                              float* __restrict__ hout) {
    int row = blockIdx.x * 4 + (threadIdx.x >> 6);
    int lane = threadIdx.x & 63;
    int n = nnz[row];
    int bbase = row & ~(NN - 1);                // (row / NN) * NN
    const int* cl = csr + row * CAP;
    float acc = 0.f;
    for (int k = 0; k < n; ++k) {
        int gj = bbase + cl[k];
        acc += dinv[gj] * m[(size_t)gj * HID + lane];   // 256B coalesced gather
    }
    float r = dinv[row] * acc + bias[lane];
    hout[(size_t)row * HID + lane] = fmaxf(r, 0.f);
}

// ---------------- K: pooled mean + relu(pooled@Wf1+bf1)@Wf2+bf2 ----------------
__global__ __launch_bounds__(256) void k_head(const float* __restrict__ h,
                                              const float* __restrict__ Wf1,
                                              const float* __restrict__ bf1,
                                              const float* __restrict__ Wf2,
                                              const float* __restrict__ bf2,
                                              float* __restrict__ out) {
    int b = blockIdx.x;
    __shared__ float sp[4][HID];
    __shared__ float pooled[HID];
    __shared__ float hid[HEADD];
    int c = threadIdx.x & 63, q = threadIdx.x >> 6;
    const float* hb = h + (size_t)b * NN * HID;
    float a = 0.f;
    for (int n = q; n < NN; n += 4) a += hb[(size_t)n * HID + c];
    sp[q][c] = a;
    __syncthreads();
    if (q == 0)
        pooled[c] = (sp[0][c] + sp[1][c] + sp[2][c] + sp[3][c]) * (1.0f / NN);
    __syncthreads();
    if (threadIdx.x < HEADD) {
        float acc = bf1[threadIdx.x];
        for (int d = 0; d < HID; ++d) acc += pooled[d] * Wf1[d * HEADD + threadIdx.x];
        hid[threadIdx.x] = fmaxf(acc, 0.f);
    }
    __syncthreads();
    if (threadIdx.x < 64) {
        float v = hid[threadIdx.x] * Wf2[threadIdx.x] +
                  hid[threadIdx.x + 64] * Wf2[threadIdx.x + 64];
#pragma unroll
        for (int off = 32; off > 0; off >>= 1) v += __shfl_down(v, off, 64);
        if (threadIdx.x == 0) out[b] = v + bf2[0];
    }
}

extern "C" void kernel_launch(void* const* d_in, const int* in_sizes, int n_in,
                              void* d_out, int out_size, void* d_ws, size_t ws_size,
                              hipStream_t stream) {
    const float* x   = (const float*)d_in[0];
    const float* adj = (const float*)d_in[1];
    const float* W1  = (const float*)d_in[2];
    const float* b1  = (const float*)d_in[3];
    const float* W2  = (const float*)d_in[4];
    const float* b2  = (const float*)d_in[5];
    const float* W3  = (const float*)d_in[6];
    const float* b3  = (const float*)d_in[7];
    const float* Wf1 = (const float*)d_in[8];
    const float* bf1 = (const float*)d_in[9];
    const float* Wf2 = (const float*)d_in[10];
    const float* bf2 = (const float*)d_in[11];
    float* out = (float*)d_out;

    // workspace carve (16B-aligned chunks), total ~25.4 MB
    char* ws = (char*)d_ws;
    int*   csr  = (int*)ws;                                   // ROWS*CAP*4 = 8 MB
    int*   nnz  = (int*)(ws + (size_t)ROWS * CAP * 4);        // 128 KB
    float* dinv = (float*)(ws + (size_t)ROWS * CAP * 4 + ROWS * 4);
    float* bufA = (float*)(ws + (size_t)ROWS * CAP * 4 + 2 * ROWS * 4);  // 8 MB
    float* bufB = bufA + (size_t)ROWS * HID;                  // 8 MB

    k_build<<<ROWS, 256, 0, stream>>>(adj, csr, nnz, dinv);
    k_xw1 <<<ROWS / 4, 256, 0, stream>>>(x, W1, bufA);
    k_spmm<<<ROWS / 4, 256, 0, stream>>>(bufA, csr, nnz, dinv, b1, bufB);
    k_hw  <<<ROWS / 16, 256, 0, stream>>>(bufB, W2, bufA);
    k_spmm<<<ROWS / 4, 256, 0, stream>>>(bufA, csr, nnz, dinv, b2, bufB);
    k_hw  <<<ROWS / 16, 256, 0, stream>>>(bufB, W3, bufA);
    k_spmm<<<ROWS / 4, 256, 0, stream>>>(bufA, csr, nnz, dinv, b3, bufB);
    k_head<<<BATCH, 256, 0, stream>>>(bufB, Wf1, bf1, Wf2, bf2, out);
}

// Round 3
// 381.895 us; speedup vs baseline: 1.1061x; 1.1061x over previous
//
#include <hip/hip_runtime.h>
#include <math.h>

#define NN 1024
#define HID 64
#define HEADD 128
#define NODE_DIM 14
#define BATCH 32
#define CAP 64
#define ROWS (BATCH * NN)   // 32768

// ---------------- K1: adjacency -> CSR + degree^-1/2 (wave-per-row, ballot) --
// 4 rows per block, one wave per row. Each lane reads 4 float4 chunks:
// 64 lanes * 4 chunks * 4 floats = 1024 columns (R2 bug: only 1 chunk = 256).
// Ballot-compaction: no LDS, no atomics. Also zeroes the pooled accumulator.
__global__ __launch_bounds__(256) void k_build(const float* __restrict__ adj,
                                               int* __restrict__ csr,
                                               int* __restrict__ nnz,
                                               float* __restrict__ dinv,
                                               float* __restrict__ pooled) {
    if (blockIdx.x < 8) pooled[blockIdx.x * 256 + threadIdx.x] = 0.0f;  // 2048 floats
    int wv = threadIdx.x >> 6, lane = threadIdx.x & 63;
    int row = blockIdx.x * 4 + wv;
    const float4* rp = reinterpret_cast<const float4*>(adj + (size_t)row * NN);
    unsigned long long lt = ((unsigned long long)1 << lane) - 1;
    int base = 0;
#pragma unroll
    for (int j = 0; j < 4; ++j) {
        float4 v = rp[lane + 64 * j];
        float vv[4] = {v.x, v.y, v.z, v.w};
#pragma unroll
        for (int k = 0; k < 4; ++k) {
            unsigned long long mk = __ballot(vv[k] != 0.0f);
            if (vv[k] != 0.0f) {
                int pos = base + __popcll(mk & lt);
                if (pos < CAP) csr[row * CAP + pos] = (lane + 64 * j) * 4 + k;
            }
            base += __popcll(mk);
        }
    }
    if (lane == 0) {
        int n = base < CAP ? base : CAP;
        nnz[row] = n;
        int d = base < 1 ? 1 : base;
        dinv[row] = 1.0f / sqrtf((float)d);
    }
}

// ---------------- K2: g1 = x @ W1  ([ROWS,14] @ [14,64]) ----------------
__global__ __launch_bounds__(256) void k_xw1(const float* __restrict__ x,
                                             const float* __restrict__ W1,
                                             float* __restrict__ g) {
    __shared__ float sW[NODE_DIM * HID];        // 3.5 KB
    __shared__ float sx[4 * NODE_DIM];
    int row0 = blockIdx.x * 4;
    for (int i = threadIdx.x; i < NODE_DIM * HID; i += 256) sW[i] = W1[i];
    for (int i = threadIdx.x; i < 4 * NODE_DIM; i += 256)
        sx[i] = x[(size_t)row0 * NODE_DIM + i];
    __syncthreads();
    int c = threadIdx.x & 63, rl = threadIdx.x >> 6;
    float acc = 0.f;
#pragma unroll
    for (int d = 0; d < NODE_DIM; ++d) acc += sx[rl * NODE_DIM + d] * sW[d * HID + c];
    g[(size_t)(row0 + rl) * HID + c] = acc;
}

// ---------------- K3: fused  g_out = relu(D A D g_in + bias) @ W ------------
// One wave per row, lane = feature. Indices+dinv prefetched per-lane then
// broadcast via shfl -> all gathers independent (pipelined). h row lives in
// registers across the wave; h@W done via shfl broadcast + LDS-staged W.
__global__ __launch_bounds__(256) void k_layer(const float* __restrict__ g_in,
                                               const int* __restrict__ csr,
                                               const int* __restrict__ nnz,
                                               const float* __restrict__ dinv,
                                               const float* __restrict__ bias,
                                               const float* __restrict__ W,
                                               float* __restrict__ g_out) {
    __shared__ float sW[HID * HID];             // 16 KB
    for (int i = threadIdx.x; i < HID * HID; i += 256) sW[i] = W[i];
    int wv = threadIdx.x >> 6, lane = threadIdx.x & 63;
    int row = blockIdx.x * 4 + wv;
    int bbase = row & ~(NN - 1);
    int n = nnz[row];
    const int* cl = csr + row * CAP;
    int idx = (lane < n) ? cl[lane] : 0;                 // coalesced prefetch
    float dv = (lane < n) ? dinv[bbase + idx] : 0.f;
    float acc = 0.f;
    for (int k = 0; k < n; ++k) {
        int gj = bbase + __shfl(idx, k);
        float w = __shfl(dv, k);
        acc += w * g_in[(size_t)gj * HID + lane];        // independent 256B gathers
    }
    float h = fmaxf(dinv[row] * acc + bias[lane], 0.f);
    __syncthreads();                                     // sW ready
    float o = 0.f;
#pragma unroll 8
    for (int d = 0; d < HID; ++d)
        o += __shfl(h, d) * sW[d * HID + lane];          // conflict-free
    g_out[(size_t)row * HID + lane] = o;
}

// ---------------- K4: last layer: h3 = relu(D A D g3 + b3); pool-accumulate -
__global__ __launch_bounds__(256) void k_layer3(const float* __restrict__ g_in,
                                                const int* __restrict__ csr,
                                                const int* __restrict__ nnz,
                                                const float* __restrict__ dinv,
                                                const float* __restrict__ bias,
                                                float* __restrict__ pooled) {
    __shared__ float sh[4][HID];
    int wv = threadIdx.x >> 6, lane = threadIdx.x & 63;
    int row = blockIdx.x * 4 + wv;
    int bbase = row & ~(NN - 1);
    int n = nnz[row];
    const int* cl = csr + row * CAP;
    int idx = (lane < n) ? cl[lane] : 0;
    float dv = (lane < n) ? dinv[bbase + idx] : 0.f;
    float acc = 0.f;
    for (int k = 0; k < n; ++k) {
        int gj = bbase + __shfl(idx, k);
        float w = __shfl(dv, k);
        acc += w * g_in[(size_t)gj * HID + lane];
    }
    sh[wv][lane] = fmaxf(dinv[row] * acc + bias[lane], 0.f);
    __syncthreads();
    if (wv == 0) {
        float s = sh[0][lane] + sh[1][lane] + sh[2][lane] + sh[3][lane];
        int b = row >> 10;                      // row / NN (rows in block share b)
        atomicAdd(&pooled[b * HID + lane], s);
    }
}

// ---------------- K5: head: mean + relu(p@Wf1+bf1)@Wf2+bf2 ------------------
__global__ __launch_bounds__(128) void k_head(const float* __restrict__ pooled_sum,
                                              const float* __restrict__ Wf1,
                                              const float* __restrict__ bf1,
                                              const float* __restrict__ Wf2,
                                              const float* __restrict__ bf2,
                                              float* __restrict__ out) {
    int b = blockIdx.x, t = threadIdx.x;        // 128 threads
    __shared__ float p[HID];
    __shared__ float hid[HEADD];
    if (t < HID) p[t] = pooled_sum[b * HID + t] * (1.0f / NN);
    __syncthreads();
    float acc = bf1[t];
    for (int d = 0; d < HID; ++d) acc += p[d] * Wf1[d * HEADD + t];
    hid[t] = fmaxf(acc, 0.f);
    __syncthreads();
    if (t < 64) {
        float v = hid[t] * Wf2[t] + hid[t + 64] * Wf2[t + 64];
#pragma unroll
        for (int off = 32; off > 0; off >>= 1) v += __shfl_down(v, off, 64);
        if (t == 0) out[b] = v + bf2[0];
    }
}

extern "C" void kernel_launch(void* const* d_in, const int* in_sizes, int n_in,
                              void* d_out, int out_size, void* d_ws, size_t ws_size,
                              hipStream_t stream) {
    const float* x   = (const float*)d_in[0];
    const float* adj = (const float*)d_in[1];
    const float* W1  = (const float*)d_in[2];
    const float* b1  = (const float*)d_in[3];
    const float* W2  = (const float*)d_in[4];
    const float* b2  = (const float*)d_in[5];
    const float* W3  = (const float*)d_in[6];
    const float* b3  = (const float*)d_in[7];
    const float* Wf1 = (const float*)d_in[8];
    const float* bf1 = (const float*)d_in[9];
    const float* Wf2 = (const float*)d_in[10];
    const float* bf2 = (const float*)d_in[11];
    float* out = (float*)d_out;

    // workspace carve: csr 8MB | nnz 128KB | dinv 128KB | pooled 16KB | bufA 8MB | bufB 8MB
    char* ws = (char*)d_ws;
    int*   csr    = (int*)ws;
    int*   nnz    = (int*)(ws + (size_t)ROWS * CAP * 4);
    float* dinv   = (float*)(ws + (size_t)ROWS * CAP * 4 + (size_t)ROWS * 4);
    float* pooled = (float*)(ws + (size_t)ROWS * CAP * 4 + (size_t)2 * ROWS * 4);
    float* bufA   = (float*)(ws + (size_t)ROWS * CAP * 4 + (size_t)2 * ROWS * 4 + 4096 * 4);
    float* bufB   = bufA + (size_t)ROWS * HID;

    k_build <<<ROWS / 4, 256, 0, stream>>>(adj, csr, nnz, dinv, pooled);
    k_xw1   <<<ROWS / 4, 256, 0, stream>>>(x, W1, bufA);                        // g1
    k_layer <<<ROWS / 4, 256, 0, stream>>>(bufA, csr, nnz, dinv, b1, W2, bufB); // g2
    k_layer <<<ROWS / 4, 256, 0, stream>>>(bufB, csr, nnz, dinv, b2, W3, bufA); // g3
    k_layer3<<<ROWS / 4, 256, 0, stream>>>(bufA, csr, nnz, dinv, b3, pooled);
    k_head  <<<BATCH, 128, 0, stream>>>(pooled, Wf1, bf1, Wf2, bf2, out);
}